// Round 6
// baseline (2153.806 us; speedup 1.0000x reference)
//
#include <hip/hip_runtime.h>

#define B_   128
#define S_   256
#define D_   512
#define L_   4
#define H_   8
#define DH_  64
#define FF_  512
#define M_   32768   // B_*S_
#define EPS_ 1e-3f

typedef unsigned short u16;
typedef unsigned int   u32;
typedef __bf16 bf16_8 __attribute__((ext_vector_type(8)));
typedef float  f32_4  __attribute__((ext_vector_type(4)));

__device__ __forceinline__ float bf2f(u16 u) {
  union { u32 i; float f; } x; x.i = ((u32)u) << 16; return x.f;
}
__device__ __forceinline__ u16 f2bf(float f) {
  union { float f; u32 i; } x; x.f = f;
  u32 r = x.i + 0x7fffu + ((x.i >> 16) & 1u);
  return (u16)(r >> 16);
}
__device__ __forceinline__ u32 pk2(float a, float b) {
  return (u32)f2bf(a) | ((u32)f2bf(b) << 16);
}
// async 16B global->LDS; lane i of the wave lands at l + i*16 bytes
__device__ __forceinline__ void async_cp16(const void* g, void* l) {
  __builtin_amdgcn_global_load_lds(
      (const __attribute__((address_space(1))) void*)g,
      (__attribute__((address_space(3))) void*)l, 16, 0, 0);
}

// ---------------- embedding: h_bf16 = bf16(embed[seq] + pos), f32 inputs ----------------
__global__ __launch_bounds__(256) void k_embed(const int* __restrict__ seq,
    const float* __restrict__ pos, const float* __restrict__ emb,
    u16* __restrict__ h)
{
  int t = blockIdx.x * 256 + threadIdx.x;   // M_*64 threads, 8 elems each
  int row = t >> 6;
  int c = (t & 63) * 8;
  int s = row & (S_ - 1);
  int tok = seq[row];
  const float* ep = emb + (size_t)tok * D_ + c;
  const float* pp = pos + (size_t)s * D_ + c;
  float4 e0 = *(const float4*)ep;
  float4 e1 = *(const float4*)(ep + 4);
  float4 p0 = *(const float4*)pp;
  float4 p1 = *(const float4*)(pp + 4);
  u32 o[4];
  o[0] = pk2(e0.x + p0.x, e0.y + p0.y);
  o[1] = pk2(e0.z + p0.z, e0.w + p0.w);
  o[2] = pk2(e1.x + p1.x, e1.y + p1.y);
  o[3] = pk2(e1.z + p1.z, e1.w + p1.w);
  *(uint4*)&h[(size_t)row * D_ + c] = make_uint4(o[0], o[1], o[2], o[3]);
}

// ------- transpose all 24 [512x512] f32 weights -> bf16 Wt[n][k] -------
__global__ __launch_bounds__(256) void k_transpose(
    const float* __restrict__ Wq, const float* __restrict__ Wk, const float* __restrict__ Wv,
    const float* __restrict__ Wo, const float* __restrict__ W1, const float* __restrict__ W2,
    u16* __restrict__ Wt)
{
  __shared__ u16 tile[32][33];
  int mat = blockIdx.z;           // 0..23
  int layer = mat / 6, w = mat % 6;
  const float* src = (w == 0) ? Wq : (w == 1) ? Wk : (w == 2) ? Wv
                   : (w == 3) ? Wo : (w == 4) ? W1 : W2;
  src += (size_t)layer * (D_ * D_);
  u16* dst = Wt + (size_t)mat * (D_ * D_);
  int bx = blockIdx.x * 32;   // n
  int by = blockIdx.y * 32;   // k
  int tx = threadIdx.x & 31, ty = threadIdx.x >> 5;
#pragma unroll
  for (int i = 0; i < 32; i += 8)
    tile[ty + i][tx] = f2bf(src[(size_t)(by + ty + i) * D_ + bx + tx]);
  __syncthreads();
#pragma unroll
  for (int i = 0; i < 32; i += 8)
    dst[(size_t)(bx + ty + i) * D_ + by + tx] = tile[tx][ty + i];
}

// ---------------- GEMM: C[M,512] = A[M,512](bf16) x Bt[n][k](bf16) + bias(f32) ----------------
// 256x256 tile, 512 threads (8 waves of 64x128), BK=32, double-buffered cp16.
// MFMA operands SWAPPED (weights first) so each lane holds 4 consecutive output
// columns -> vectorized 8B/16B stores.
// mode 0: outb bf16 = A*B + bias                      (row-major [M,512])
// mode 1: outb bf16 = relu(A*B + bias)                (row-major [M,512])
// mode 2: outf f32  = A*B + bias + resid(bf16), fused BN-stat atomics into stats[]
// mode 3: outb bf16 = A*B + bias, head-blocked [b,h,s,dh] (for q/k/v)
__global__ __launch_bounds__(512, 2) void k_gemm(
    const u16* __restrict__ A, const u16* __restrict__ Bt,
    const float* __restrict__ bias, const u16* __restrict__ resid,
    u16* __restrict__ outb, float* __restrict__ outf, float* __restrict__ stats,
    int mode)
{
  __shared__ u16 As[2 * 256 * 32];   // 32 KB
  __shared__ u16 Bs[2 * 256 * 32];   // 32 KB
  int tid = threadIdx.x;
  int m0 = blockIdx.x * 256;
  int n0 = blockIdx.y * 256;
  int w = tid >> 6, lane = tid & 63;
  int wm = (w & 3) * 64, wn = (w >> 2) * 128;
  int fr = lane & 15, lk = lane >> 4;

  // staging: wave w stages rows [w*32, w*32+32) of A and B tiles (2 cp16 each).
  int srow = lane >> 2;                          // 0..15
  int schunk = (lane & 3) ^ ((srow >> 2) & 3);   // XOR-swizzled 16B chunk
  const u16* Ag0 = A  + (size_t)(m0 + w * 32 + srow) * 512 + schunk * 8;
  const u16* Ag1 = Ag0 + (size_t)16 * 512;
  const u16* Bg0 = Bt + (size_t)(n0 + w * 32 + srow) * 512 + schunk * 8;
  const u16* Bg1 = Bg0 + (size_t)16 * 512;
  int off0 = (w * 32) * 32;
  int off1 = (w * 32 + 16) * 32;

  f32_4 acc[4][8] = {};
  int ach = (lk ^ ((fr >> 2) & 3)) * 8;          // frag chunk after swizzle

  async_cp16(Ag0, &As[off0]);
  async_cp16(Ag1, &As[off1]);
  async_cp16(Bg0, &Bs[off0]);
  async_cp16(Bg1, &Bs[off1]);

  for (int it = 0; it < 16; it++) {
    int p = it & 1;
    const u16* Ab = &As[p * 8192];
    const u16* Bb = &Bs[p * 8192];
    __syncthreads();                 // drains vmcnt: buffer p ready
    if (it < 15) {
      int kn = (it + 1) * 32;
      int pn = (p ^ 1) * 8192;
      async_cp16(Ag0 + kn, &As[pn + off0]);
      async_cp16(Ag1 + kn, &As[pn + off1]);
      async_cp16(Bg0 + kn, &Bs[pn + off0]);
      async_cp16(Bg1 + kn, &Bs[pn + off1]);
    }
    bf16_8 afr[4], bfr[8];
#pragma unroll
    for (int i = 0; i < 4; i++)
      afr[i] = *(const bf16_8*)&Ab[(wm + i * 16 + fr) * 32 + ach];
#pragma unroll
    for (int j = 0; j < 8; j++)
      bfr[j] = *(const bf16_8*)&Bb[(wn + j * 16 + fr) * 32 + ach];
#pragma unroll
    for (int i = 0; i < 4; i++)
#pragma unroll
      for (int j = 0; j < 8; j++)
        acc[i][j] = __builtin_amdgcn_mfma_f32_16x16x32_bf16(bfr[j], afr[i], acc[i][j], 0, 0, 0);
  }

  // epilogue: lane holds cols nb..nb+3 at rows m0+wm+i*16+fr
#pragma unroll
  for (int j = 0; j < 8; j++) {
    int nb = n0 + wn + j * 16 + lk * 4;
    float4 bv = *(const float4*)&bias[nb];
    float csum[4] = {0.f, 0.f, 0.f, 0.f}, csq[4] = {0.f, 0.f, 0.f, 0.f};
#pragma unroll
    for (int i = 0; i < 4; i++) {
      int m = m0 + wm + i * 16 + fr;
      float c0 = acc[i][j][0] + bv.x;
      float c1 = acc[i][j][1] + bv.y;
      float c2 = acc[i][j][2] + bv.z;
      float c3 = acc[i][j][3] + bv.w;
      if (mode == 1) {
        c0 = fmaxf(c0, 0.f); c1 = fmaxf(c1, 0.f);
        c2 = fmaxf(c2, 0.f); c3 = fmaxf(c3, 0.f);
      }
      if (mode == 2) {
        size_t idx = (size_t)m * 512 + nb;
        uint2 rv = *(const uint2*)&resid[idx];
        c0 += bf2f((u16)(rv.x & 0xffff)); c1 += bf2f((u16)(rv.x >> 16));
        c2 += bf2f((u16)(rv.y & 0xffff)); c3 += bf2f((u16)(rv.y >> 16));
        *(float4*)&outf[idx] = make_float4(c0, c1, c2, c3);
        csum[0] += c0; csq[0] = fmaf(c0, c0, csq[0]);
        csum[1] += c1; csq[1] = fmaf(c1, c1, csq[1]);
        csum[2] += c2; csq[2] = fmaf(c2, c2, csq[2]);
        csum[3] += c3; csq[3] = fmaf(c3, c3, csq[3]);
      } else if (mode == 3) {
        int bb = m >> 8, s = m & 255, hh = nb >> 6, dh = nb & 63;
        size_t idx = ((size_t)(bb * 8 + hh) * 256 + s) * 64 + dh;
        *(uint2*)&outb[idx] = make_uint2(pk2(c0, c1), pk2(c2, c3));
      } else {
        *(uint2*)&outb[(size_t)m * 512 + nb] = make_uint2(pk2(c0, c1), pk2(c2, c3));
      }
    }
    if (mode == 2) {
#pragma unroll
      for (int r = 0; r < 4; r++) {
        float s = csum[r], qq = csq[r];
        s += __shfl_xor(s, 1); s += __shfl_xor(s, 2);
        s += __shfl_xor(s, 4); s += __shfl_xor(s, 8);
        qq += __shfl_xor(qq, 1); qq += __shfl_xor(qq, 2);
        qq += __shfl_xor(qq, 4); qq += __shfl_xor(qq, 8);
        if (fr == 0) {
          atomicAdd(&stats[nb + r], s);
          atomicAdd(&stats[512 + nb + r], qq);
        }
      }
    }
  }
}

// ---------------- MFMA attention ----------------
// q/k/v head-blocked [b,h,s,dh]. Grid 1024 = (b,h). K,V staged in LDS once;
// 4 waves x 4 q-tiles; swapped operands (softmax per-lane row, 8B stores).
// LDS 72 KB -> 2 blocks/CU.
__global__ __launch_bounds__(256) void k_attn(
    const u16* __restrict__ q, const u16* __restrict__ k,
    const u16* __restrict__ v, u16* __restrict__ attn)
{
  __shared__ u16 Ks[256 * 64];        // 32 KB; chunk c of row holds global c^(row&7)
  __shared__ u16 Vt[64 * 256];        // 32 KB; chunk ck of d-row holds global ck^(row&31)
  __shared__ u16 Pm[4][16 * 64];      // 8 KB; per-wave quarter-P, chunk c^(row&7)
  int tid = threadIdx.x;
  int h = blockIdx.x & 7, b = blockIdx.x >> 3;
  size_t hb = (size_t)(b * 8 + h) * (256 * 64);
  int w = tid >> 6, lane = tid & 63;

  // ---- stage K via async cp16, swizzled on the global-address side ----
#pragma unroll
  for (int it = 0; it < 8; it++) {
    int row = it * 32 + w * 8 + (lane >> 3);
    int c = lane & 7;
    const u16* src = k + hb + (size_t)row * 64 + ((c ^ (row & 7)) * 8);
    async_cp16(src, &Ks[(it * 32 + w * 8) * 64]);
  }

  // ---- stage V transposed: Vt[d][key], keys packed pairwise as u32 ----
  {
    int kp = tid & 127;          // key pair index (keys 2kp, 2kp+1)
    int o  = tid >> 7;           // d half
    const u16* vp = v + hb + (size_t)(2 * kp) * 64 + o * 32;
    union { uint4 u[4]; u16 s[32]; } r0, r1;
#pragma unroll
    for (int i = 0; i < 4; i++) {
      r0.u[i] = *(const uint4*)(vp + i * 8);
      r1.u[i] = *(const uint4*)(vp + 64 + i * 8);
    }
#pragma unroll
    for (int d = 0; d < 32; d++) {
      int da = o * 32 + d;
      u32 val = (u32)r0.s[d] | ((u32)r1.s[d] << 16);
      int idx = da * 256 + ((((kp >> 2) ^ (da & 31)) << 3)) + ((2 * kp) & 7);
      *(u32*)&Vt[idx] = val;
    }
  }
  __syncthreads();   // drains cp16 vmcnt + Vt ds_writes

  int fr = lane & 15;          // q-row within tile (also frag read row)
  int lk = lane >> 4;

#pragma unroll 1
  for (int qt = 0; qt < 4; qt++) {
    int q0 = qt * 64 + w * 16;

    // ---- QK^T (swapped: K first) -> accS[j] regs = keys j*16+lk*4+r, q = fr ----
    f32_4 accS[16];
    const u16* qbase = q + hb + (size_t)(q0 + fr) * 64 + lk * 8;
    bf16_8 af0 = *(const bf16_8*)(qbase);
    bf16_8 af1 = *(const bf16_8*)(qbase + 32);
#pragma unroll
    for (int j = 0; j < 16; j++) {
      int rx = j * 16 + fr;
      bf16_8 bf0 = *(const bf16_8*)&Ks[rx * 64 + ((lk ^ (fr & 7)) << 3)];
      bf16_8 bf1 = *(const bf16_8*)&Ks[rx * 64 + (((lk + 4) ^ (fr & 7)) << 3)];
      f32_4 z = {};
      z = __builtin_amdgcn_mfma_f32_16x16x32_bf16(bf0, af0, z, 0, 0, 0);
      accS[j] = __builtin_amdgcn_mfma_f32_16x16x32_bf16(bf1, af1, z, 0, 0, 0);
    }

    // ---- softmax: each lane owns q-row fr, 64 of 256 keys; reduce over lk ----
    float mx = -1e30f;
#pragma unroll
    for (int j = 0; j < 16; j++) {
      mx = fmaxf(mx, fmaxf(fmaxf(accS[j][0], accS[j][1]), fmaxf(accS[j][2], accS[j][3])));
    }
    mx = fmaxf(mx, __shfl_xor(mx, 16));
    mx = fmaxf(mx, __shfl_xor(mx, 32));
    float sum = 0.f;
#pragma unroll
    for (int j = 0; j < 16; j++) {
#pragma unroll
      for (int r = 0; r < 4; r++) {
        float p = __expf((accS[j][r] - mx) * 0.125f);   // 1/sqrt(64)
        accS[j][r] = p;
        sum += p;
      }
    }
    sum += __shfl_xor(sum, 16);
    sum += __shfl_xor(sum, 32);
    float linv = 1.f / sum;

    // ---- PV in 4 quarter-passes (64 keys each) through wave-private Pm ----
    f32_4 accO[4] = {};
#pragma unroll
    for (int qd = 0; qd < 4; qd++) {
      // write P quarter: row = fr, local keys jl*16+lk*4+{0..3}
#pragma unroll
      for (int jl = 0; jl < 4; jl++) {
        int j = qd * 4 + jl;
        int kl = jl * 16 + lk * 4;
        int ch = kl >> 3;
        int idx = fr * 64 + ((ch ^ (fr & 7)) << 3) + (kl & 7);
        *(uint2*)&Pm[w][idx] = make_uint2(pk2(accS[j][0], accS[j][1]),
                                          pk2(accS[j][2], accS[j][3]));
      }
      // PV (swapped: Vt first) over this quarter's 64 keys
#pragma unroll
      for (int kk = 0; kk < 2; kk++) {
        int ch = kk * 4 + lk;
        bf16_8 pa = *(const bf16_8*)&Pm[w][fr * 64 + ((ch ^ (fr & 7)) << 3)];
        int ckg = qd * 8 + kk * 4 + lk;
#pragma unroll
        for (int jd = 0; jd < 4; jd++) {
          int brow = jd * 16 + fr;
          bf16_8 vb = *(const bf16_8*)&Vt[brow * 256 + ((ckg ^ (brow & 31)) << 3)];
          accO[jd] = __builtin_amdgcn_mfma_f32_16x16x32_bf16(vb, pa, accO[jd], 0, 0, 0);
        }
      }
    }

    // ---- store: lane owns q-row q0+fr, 4 consecutive d per jd -> 8B stores ----
    size_t m = (size_t)(b * S_ + q0 + fr);
#pragma unroll
    for (int jd = 0; jd < 4; jd++) {
      int d0 = h * DH_ + jd * 16 + lk * 4;
      *(uint2*)&attn[m * D_ + d0] =
          make_uint2(pk2(accO[jd][0] * linv, accO[jd][1] * linv),
                     pk2(accO[jd][2] * linv, accO[jd][3] * linv));
    }
  }
}

// ---------------- batchnorm ----------------
__global__ __launch_bounds__(256) void k_zero(float* p, int n) {
  int t = blockIdx.x * 256 + threadIdx.x;
  if (t < n) p[t] = 0.f;
}

// 8 elems/thread; writes bf16 (outb) when outf==nullptr, else f32 (final layer)
__global__ __launch_bounds__(256) void k_bnapply(const float* __restrict__ P,
    const float* __restrict__ stats, const float* __restrict__ gamma,
    const float* __restrict__ beta, u16* __restrict__ outb, float* __restrict__ outf)
{
  size_t t8 = ((size_t)blockIdx.x * 256 + threadIdx.x) * 8;
  int f = (int)(t8 & 511);
  const float inv = 1.f / 32768.f;
  float sc[8], sh[8];
#pragma unroll
  for (int i = 0; i < 8; i++) {
    float mu = stats[f + i] * inv;
    float var = stats[512 + f + i] * inv - mu * mu;
    sc[i] = gamma[f + i] * rsqrtf(var + EPS_);
    sh[i] = beta[f + i] - mu * sc[i];
  }
  float4 p0 = *(const float4*)&P[t8];
  float4 p1 = *(const float4*)&P[t8 + 4];
  float o[8] = {p0.x * sc[0] + sh[0], p0.y * sc[1] + sh[1],
                p0.z * sc[2] + sh[2], p0.w * sc[3] + sh[3],
                p1.x * sc[4] + sh[4], p1.y * sc[5] + sh[5],
                p1.z * sc[6] + sh[6], p1.w * sc[7] + sh[7]};
  if (outf) {
    *(float4*)&outf[t8]     = make_float4(o[0], o[1], o[2], o[3]);
    *(float4*)&outf[t8 + 4] = make_float4(o[4], o[5], o[6], o[7]);
  } else {
    *(uint4*)&outb[t8] = make_uint4(pk2(o[0], o[1]), pk2(o[2], o[3]),
                                    pk2(o[4], o[5]), pk2(o[6], o[7]));
  }
}

// ---------------- launch ----------------
extern "C" void kernel_launch(void* const* d_in, const int* in_sizes, int n_in,
                              void* d_out, int out_size, void* d_ws, size_t ws_size,
                              hipStream_t stream)
{
  const int*   seq = (const int*)d_in[0];
  const float* pos = (const float*)d_in[1];
  const float* emb = (const float*)d_in[2];
  const float* Wq  = (const float*)d_in[3];
  const float* bq  = (const float*)d_in[4];
  const float* Wk  = (const float*)d_in[5];
  const float* bk  = (const float*)d_in[6];
  const float* Wv  = (const float*)d_in[7];
  const float* bv  = (const float*)d_in[8];
  const float* Wo  = (const float*)d_in[9];
  const float* bo  = (const float*)d_in[10];
  const float* g1  = (const float*)d_in[11];
  const float* be1 = (const float*)d_in[12];
  const float* W1  = (const float*)d_in[13];
  const float* b1  = (const float*)d_in[14];
  const float* W2  = (const float*)d_in[15];
  const float* b2  = (const float*)d_in[16];
  const float* g2  = (const float*)d_in[17];
  const float* be2 = (const float*)d_in[18];

  char* ws = (char*)d_ws;
  const size_t SZH = (size_t)M_ * D_ * 2;        // 32 MiB per bf16 activation
  u16* hb16 = (u16*)(ws);                        // master activation (bf16)
  u16* qB   = (u16*)(ws + SZH);
  u16* kB   = (u16*)(ws + 2 * SZH);
  u16* vB   = (u16*)(ws + 3 * SZH);
  u16* aB   = (u16*)(ws + 4 * SZH);
  float* PB = (float*)(ws + 2 * SZH);            // f32 pre-BN, overlays kB,vB (dead then)
  u16* tB   = qB;                                // FFN hidden reuses q
  u16* Wt   = (u16*)(ws + 5 * SZH);
  float* stats = (float*)(ws + 5 * SZH + (size_t)24 * D_ * D_ * 2);

  dim3 blk(256);
  k_zero<<<32, blk, 0, stream>>>(stats, 8192);
  k_transpose<<<dim3(16, 16, 24), blk, 0, stream>>>(Wq, Wk, Wv, Wo, W1, W2, Wt);
  k_embed<<<M_ * 64 / 256, blk, 0, stream>>>(seq, pos, emb, hb16);

  dim3 ggrid(M_ / 256, 2);
  dim3 gblk(512);
  for (int l = 0; l < L_; l++) {
    const u16* wtq = Wt + (size_t)(l * 6 + 0) * D_ * D_;
    const u16* wtk = Wt + (size_t)(l * 6 + 1) * D_ * D_;
    const u16* wtv = Wt + (size_t)(l * 6 + 2) * D_ * D_;
    const u16* wto = Wt + (size_t)(l * 6 + 3) * D_ * D_;
    const u16* wt1 = Wt + (size_t)(l * 6 + 4) * D_ * D_;
    const u16* wt2 = Wt + (size_t)(l * 6 + 5) * D_ * D_;
    float* st = stats + l * 2048;

    k_gemm<<<ggrid, gblk, 0, stream>>>(hb16, wtq, bq + l * D_, nullptr, qB, nullptr, nullptr, 3);
    k_gemm<<<ggrid, gblk, 0, stream>>>(hb16, wtk, bk + l * D_, nullptr, kB, nullptr, nullptr, 3);
    k_gemm<<<ggrid, gblk, 0, stream>>>(hb16, wtv, bv + l * D_, nullptr, vB, nullptr, nullptr, 3);
    k_attn<<<B_ * H_, blk, 0, stream>>>(qB, kB, vB, aB);
    k_gemm<<<ggrid, gblk, 0, stream>>>(aB, wto, bo + l * D_, hb16, nullptr, PB, st, 2);
    k_bnapply<<<8192, blk, 0, stream>>>(PB, st, g1 + l * D_, be1 + l * D_, hb16, nullptr);
    k_gemm<<<ggrid, gblk, 0, stream>>>(hb16, wt1, b1 + l * FF_, nullptr, tB, nullptr, nullptr, 1);
    k_gemm<<<ggrid, gblk, 0, stream>>>(tB, wt2, b2 + l * D_, hb16, nullptr, PB, st + 1024, 2);
    if (l == L_ - 1)
      k_bnapply<<<8192, blk, 0, stream>>>(PB, st + 1024, g2 + l * D_, be2 + l * D_, nullptr, (float*)d_out);
    else
      k_bnapply<<<8192, blk, 0, stream>>>(PB, st + 1024, g2 + l * D_, be2 + l * D_, hb16, nullptr);
  }
}